// Round 15
// baseline (250.286 us; speedup 1.0000x reference)
//
#include <hip/hip_runtime.h>
#include <hip/hip_bf16.h>
#include <math.h>

#define B 8
#define C 64
#define NN 4096
#define O 64
#define KNN 20

typedef float f32x4 __attribute__((ext_vector_type(4)));
typedef short short8_t __attribute__((ext_vector_type(8)));

__device__ inline uint32_t fkey(float f) {
    uint32_t u = __float_as_uint(f);
    return u ^ (((uint32_t)((int32_t)u >> 31)) | 0x80000000u);
}

__device__ inline uint32_t med3u(uint32_t a, uint32_t b, uint32_t c) {
    uint32_t r;
    asm("v_med3_u32 %0, %1, %2, %3" : "=v"(r) : "v"(a), "v"(b), "v"(c));
    return r;
}
__device__ inline uint32_t umax(uint32_t a, uint32_t b) { return a > b ? a : b; }
__device__ inline uint32_t umin(uint32_t a, uint32_t b) { return a < b ? a : b; }

// min-reduce over each 16-lane group, result in ALL 16 lanes. Pure VALU (DPP).
__device__ inline uint32_t minall16(uint32_t v) {
    uint32_t t;
    t = (uint32_t)__builtin_amdgcn_update_dpp(0, (int)v, 0x140, 0xF, 0xF, true); // row_mirror
    v = umin(v, t);
    t = (uint32_t)__builtin_amdgcn_update_dpp(0, (int)v, 0x141, 0xF, 0xF, true); // row_half_mirror
    v = umin(v, t);
    t = (uint32_t)__builtin_amdgcn_update_dpp(0, (int)v, 0x4E, 0xF, 0xF, true);  // quad_perm [2,3,0,1]
    v = umin(v, t);
    t = (uint32_t)__builtin_amdgcn_update_dpp(0, (int)v, 0xB1, 0xF, 0xF, true);  // quad_perm [1,0,3,2]
    v = umin(v, t);
    return v;
}

// tiled xh layout: element (n, c) -> tile(n>>4)*1024 + (c>>5)*512
//                                  + ((c&31)>>3)*128 + (n&15)*8 + (c&7)
// MFMA fragment loads are lane-contiguous: lane l reads 16B at tilebase+l*16B.

// ---------------- K1: x (B,C,N) -> xt f32 (B,N,C) + xh bf16 TILED, xx = sum_c x^2 ----------------
__global__ __launch_bounds__(256) void k1_split(const float* __restrict__ x,
                                                float* __restrict__ xt,
                                                __hip_bfloat16* __restrict__ xh,
                                                float* __restrict__ xx) {
    __shared__ float tile[64][65];
    int b  = blockIdx.x / (NN / 64);
    int n0 = (blockIdx.x % (NN / 64)) * 64;
    int t = threadIdx.x;
    #pragma unroll
    for (int it = 0; it < 16; ++it) {
        int i = it * 256 + t;
        int c = i >> 6, n = i & 63;
        tile[c][n] = x[(size_t)b * C * NN + (size_t)c * NN + n0 + n];
    }
    __syncthreads();
    #pragma unroll
    for (int it = 0; it < 16; ++it) {
        int i = it * 256 + t;
        int n = i >> 6, c = i & 63;
        float v = tile[c][n];
        xt[((size_t)(b * NN + n0 + n)) * C + c] = v;
        int tl   = (n0 + n) >> 4;
        int r    = n & 15;
        int half = c >> 5, cc = c & 31;
        int grp  = cc >> 3, e = cc & 7;
        size_t ta = (size_t)b * NN * 64 + (size_t)tl * 1024 + half * 512
                  + grp * 128 + r * 8 + e;
        xh[ta] = __float2bfloat16(v);
    }
    if (t < 64) {
        float s = 0.f;
        #pragma unroll
        for (int c = 0; c < 64; ++c) { float v = tile[c][t]; s = fmaf(v, v, s); }
        xx[(size_t)b * NN + t + n0] = s;
    }
}

// ---------------- K2: 2-way strip split + rank-sum union ----------------
// Grid 1024 (4 blocks/CU target). Block = 4 waves = 2 pairs; pair p serves
// queries n0blk+p*16..+15; wave strip s = w&1 sweeps candidates [s*2048,(s+1)*2048).
// Per wave: tiled lane-contiguous sweep (128 tiles, 4-deep prefetch), per-lane
// depth-12 min-queues (lane share of strip-top-32: Binom(32,1/16) lam=2,
// P(>=13)~2e-7), 32-round DPP extraction -> strip-approx-top-32 pool.
// UNION WITHOUT MERGE: each wave exact-f32-reranks ITS pool (8 entries/lane,
// Round-1 arithmetic), writes exact keys to LDS; after barrier each entry's
// global rank = #better among the pair's 64 entries (strips disjoint -> unique);
// rank<20 scattered by both waves = exact top-20 of union. Capture is strictly
// safer than passing R8 (strip share <=20 of true top-20 vs pool 32).
__global__ __launch_bounds__(256) void k2_knn(const __hip_bfloat16* __restrict__ xh,
                                              const float* __restrict__ xt,
                                              const float* __restrict__ xx,
                                              int* __restrict__ idx) {
    int b     = blockIdx.x & 7;
    int n0blk = (blockIdx.x >> 3) << 5;        // 32 queries per block
    int t = threadIdx.x;
    int w = t >> 6, lane = t & 63;
    int laneid = lane & 15, grp = lane >> 4;
    int pairq = w >> 1, strip = w & 1;
    int n0w = n0blk + pairq * 16;              // this wave's 16 queries
    int s0  = strip * 2048;                    // strip candidate base

    const __hip_bfloat16* xhtb = xh + (size_t)b * NN * 64;   // tiled
    const float* xxb = xx + (size_t)b * NN;
    const float* xtb = xt + (size_t)b * NN * 64;

    const __hip_bfloat16* lp  = xhtb + lane * 8;             // lane base
    const __hip_bfloat16* lps = lp + (size_t)strip * 128 * 1024;  // strip base

    // A fragments: query tile n0w>>4, lane-linear
    short8_t Ah0 = *(const short8_t*)(lp + (size_t)(n0w >> 4) * 1024);
    short8_t Ah1 = *(const short8_t*)(lp + (size_t)(n0w >> 4) * 1024 + 512);

    // per-query bias: -xxq - 2  (group's queries are n0w+grp*4+j)
    float bq[4];
    #pragma unroll
    for (int j = 0; j < 4; ++j) bq[j] = -2.f - xxb[n0w + grp * 4 + j];

    // per-lane sorted min-queues (ascending), packed (key20|col12)
    uint32_t qq[4][12];
    #pragma unroll
    for (int j = 0; j < 4; ++j)
        #pragma unroll
        for (int i = 0; i < 12; ++i) qq[j][i] = 0xFFFFFFFFu;

    // ---- sweep: 128 tiles, 4-deep register pipeline, contiguous loads ----
    short8_t P00, P01, P10, P11, P20, P21, P30, P31;
    float Px0, Px1, Px2, Px3;
    P00 = *(const short8_t*)(lps);        P01 = *(const short8_t*)(lps + 512);
    P10 = *(const short8_t*)(lps + 1024); P11 = *(const short8_t*)(lps + 1536);
    P20 = *(const short8_t*)(lps + 2048); P21 = *(const short8_t*)(lps + 2560);
    P30 = *(const short8_t*)(lps + 3072); P31 = *(const short8_t*)(lps + 3584);
    Px0 = xxb[s0 + laneid];      Px1 = xxb[s0 + laneid + 16];
    Px2 = xxb[s0 + laneid + 32]; Px3 = xxb[s0 + laneid + 48];

// body K: compute tile tt+K, prefetch tile tt+4+K (lane-contiguous, imm offsets).
// Tail prefetches read <=16KB past the strip into adjacent allocated workspace
// (next strip / next batch / idx) — values never consumed.
#define SWEEP_BODY(PB0, PB1, PXX, K, PF, OFF)                                  \
    {                                                                          \
        float xxc = PXX;                                                       \
        f32x4 acc = {0.f, 0.f, 0.f, 0.f};                                      \
        acc = __builtin_amdgcn_mfma_f32_16x16x32_bf16(Ah0, PB0, acc, 0, 0, 0); \
        acc = __builtin_amdgcn_mfma_f32_16x16x32_bf16(Ah1, PB1, acc, 0, 0, 0); \
        PB0 = *(const short8_t*)(PF + OFF);                                    \
        PB1 = *(const short8_t*)(PF + OFF + 512);                              \
        PXX = xxb[ci0 + (4 + K) * 16];                                         \
        uint32_t ci = (uint32_t)(ci0 + K * 16);                                \
        _Pragma("unroll")                                                      \
        for (int j = 0; j < 4; ++j) {                                          \
            uint32_t u = __float_as_uint(fmaf(acc[j], 2.f, bq[j] - xxc));      \
            uint32_t nv = (u & 0xFFFFF000u) | ci;                              \
            _Pragma("unroll")                                                  \
            for (int i = 11; i >= 1; --i)                                      \
                qq[j][i] = med3u(qq[j][i - 1], qq[j][i], nv);                  \
            qq[j][0] = umin(qq[j][0], nv);                                     \
        }                                                                      \
    }

    #pragma unroll 1
    for (int tt = 0; tt < 128; tt += 4) {
        int ci0 = s0 + tt * 16 + laneid;
        const __hip_bfloat16* pf0 = lps + (size_t)(tt + 4) * 1024;
        const __hip_bfloat16* pf2 = pf0 + 2048;
        SWEEP_BODY(P00, P01, Px0, 0, pf0, 0)
        SWEEP_BODY(P10, P11, Px1, 1, pf0, 1024)
        SWEEP_BODY(P20, P21, Px2, 2, pf2, 0)
        SWEEP_BODY(P30, P31, Px3, 3, pf2, 1024)
    }
#undef SWEEP_BODY

    __shared__ uint32_t cand[4][16][33];   // per-wave pools (padded stride 33)
    __shared__ uint32_t rkk[4][16][33];    // exact f32 keys (padded)
    __shared__ float qrow[2][16][68];      // per-pair f32 query rows (padded)

    // stage f32 query rows (one wave per pair; visibility via the barrier)
    if (strip == 0) {
        #pragma unroll
        for (int i = 0; i < 16; ++i)
            qrow[pairq][i][lane] = xtb[(size_t)(n0w + i) * 64 + lane];
    }

    // ---- extraction: 32-round DPP min-tournament over 16 queue heads ----
    #pragma unroll 1
    for (int r = 0; r < 32; ++r) {
        #pragma unroll
        for (int j = 0; j < 4; ++j) {
            uint32_t bk = minall16(qq[j][0]);
            bool win = (qq[j][0] == bk);   // packed values unique -> single winner
            #pragma unroll
            for (int i = 0; i < 11; ++i) qq[j][i] = win ? qq[j][i + 1] : qq[j][i];
            qq[j][11] = win ? 0xFFFFFFFFu : qq[j][11];
            if (laneid == 0) cand[w][grp * 4 + j][r] = bk & 4095u;
        }
    }
    __syncthreads();

    // ---- exact f32 rerank of OWN 32-pool (Round-1 arithmetic), 8 entries/lane ----
    int rq = lane >> 2, rs = lane & 3;     // 16 queries x 4 lanes each
    float qxx = xxb[n0w + rq];
    const float4* qr = (const float4*)qrow[pairq][rq];
    uint32_t ky[8], cl[8];
    #pragma unroll
    for (int e = 0; e < 8; ++e) {
        uint32_t col = cand[w][rq][rs + 4 * e];
        const float4* cr = (const float4*)(xtb + (size_t)col * 64);
        float a = 0.f;
        #pragma unroll
        for (int i = 0; i < 16; ++i) {
            float4 qv = qr[i], cv = cr[i];
            a = fmaf(qv.x, cv.x, a); a = fmaf(qv.y, cv.y, a);
            a = fmaf(qv.z, cv.z, a); a = fmaf(qv.w, cv.w, a);
        }
        float d = 2.f * a - qxx - xxb[col];
        ky[e] = fkey(d);
        cl[e] = col;
        rkk[w][rq][rs + 4 * e] = ky[e];
    }
    __syncthreads();   // CRITICAL: pair's rkk/cand must be complete

    // ---- rank-sum union: global rank vs the pair's 64 entries ----
    int wp0 = w & ~1;
    int rank[8];
    #pragma unroll
    for (int e = 0; e < 8; ++e) rank[e] = 0;
    #pragma unroll
    for (int jj = 0; jj < 64; ++jj) {
        int wp = wp0 + (jj >> 5), slot = jj & 31;
        uint32_t kj = rkk[wp][rq][slot], cj = cand[wp][rq][slot];
        #pragma unroll
        for (int e = 0; e < 8; ++e)
            rank[e] += (kj > ky[e] || (kj == ky[e] && cj < cl[e])) ? 1 : 0;
    }
    size_t ob = ((size_t)(b * NN) + n0w + rq) * KNN;
    #pragma unroll
    for (int e = 0; e < 8; ++e)
        if (rank[e] < KNN) idx[ob + rank[e]] = (int)cl[e];
}

// ---------------- K3a: Z = xt @ W0^T, Z2 = xt @ (W1-W0)^T ----------------
__global__ __launch_bounds__(256) void k3a_gemm(const float* __restrict__ xt,
                                                const float* __restrict__ W,
                                                float* __restrict__ Z,
                                                float* __restrict__ Z2) {
    __shared__ float W0t[64][65];
    __shared__ float W21t[64][65];
    __shared__ float xs[16][64];
    int t = threadIdx.x;
    #pragma unroll
    for (int it = 0; it < 16; ++it) {
        int i = it * 256 + t;
        int o = i >> 6, c = i & 63;
        float w0 = W[o * 128 + c];
        float w1 = W[o * 128 + 64 + c];
        W0t[c][o]  = w0;
        W21t[c][o] = w1 - w0;
    }
    int b  = blockIdx.x / (NN / 16);
    int nb = (blockIdx.x % (NN / 16)) * 16;
    #pragma unroll
    for (int it = 0; it < 4; ++it) {
        int i = it * 256 + t;
        int r = i >> 6, c = i & 63;
        xs[r][c] = xt[((size_t)(b * NN + nb + r)) * C + c];
    }
    __syncthreads();
    int o = t & 63, rg = t >> 6;
    #pragma unroll
    for (int rr = 0; rr < 4; ++rr) {
        int r = rg * 4 + rr;
        float z = 0.f, z2 = 0.f;
        #pragma unroll
        for (int c = 0; c < 64; ++c) {
            float xv = xs[r][c];
            z  = fmaf(xv, W0t[c][o],  z);
            z2 = fmaf(xv, W21t[c][o], z2);
        }
        size_t off = ((size_t)(b * NN + nb + r)) * 64 + o;
        Z[off]  = z;
        Z2[off] = z2;
    }
}

// ---------------- K3b: gather neighbors, per-(b,n,o) max/min over k, block-partial sums ----------------
// XCD swizzle: b = blockIdx&7 pins each batch's Z/Z2 (2MB) to one XCD's L2.
__global__ __launch_bounds__(256) void k3b_gather(const float* __restrict__ Z,
                                                  const float* __restrict__ Z2,
                                                  const int* __restrict__ idx,
                                                  float* __restrict__ maxY,
                                                  float* __restrict__ minY,
                                                  float* __restrict__ partials) {
    int t = threadIdx.x;
    int p = t >> 6, o = t & 63;
    int b = blockIdx.x & 7;
    int n = (blockIdx.x >> 3) * 4 + p;
    size_t base = (size_t)(b * NN + n);
    float z2 = Z2[base * 64 + o];
    __shared__ int sidx[4][KNN];
    if (o < KNN) sidx[p][o] = idx[base * KNN + o];
    __syncthreads();
    const float* Zb = Z + (size_t)b * NN * 64;
    float s1 = 0.f, s2 = 0.f, mx = -INFINITY, mn = INFINITY;
    #pragma unroll
    for (int k = 0; k < KNN; ++k) {
        float y = Zb[(size_t)sidx[p][k] * 64 + o] + z2;
        s1 += y;
        s2 = fmaf(y, y, s2);
        mx = fmaxf(mx, y);
        mn = fminf(mn, y);
    }
    maxY[base * 64 + o] = mx;
    minY[base * 64 + o] = mn;
    __shared__ float red[2][4][64];
    red[0][p][o] = s1;
    red[1][p][o] = s2;
    __syncthreads();
    if (t < 64) {
        float a = red[0][0][t] + red[0][1][t] + red[0][2][t] + red[0][3][t];
        float c = red[1][0][t] + red[1][1][t] + red[1][2][t] + red[1][3][t];
        partials[(size_t)blockIdx.x * 128 + t]      = a;
        partials[(size_t)blockIdx.x * 128 + 64 + t] = c;
    }
}

// ---------------- K4a: reduce 8192 partial rows -> 64 rows ----------------
__global__ __launch_bounds__(256) void k4a_reduce(const float* __restrict__ partials,
                                                  float* __restrict__ partials2) {
    int g = blockIdx.x;          // 0..63
    int t = threadIdx.x;
    int col = t & 127, half = t >> 7;
    float s = 0.f;
    for (int r = half; r < 128; r += 2)
        s += partials[((size_t)g * 128 + r) * 128 + col];
    __shared__ float red[2][128];
    red[half][col] = s;
    __syncthreads();
    if (t < 128) partials2[(size_t)g * 128 + t] = red[0][t] + red[1][t];
}

// ---------------- K4b: final stats -> scale/shift per channel ----------------
__global__ __launch_bounds__(128) void k4b_stats(const float* __restrict__ partials2,
                                                 const float* __restrict__ gamma,
                                                 const float* __restrict__ beta,
                                                 float* __restrict__ ss) {
    int t = threadIdx.x;   // 0..127
    double s = 0.0;
    for (int i = 0; i < 64; ++i)
        s += (double)partials2[(size_t)i * 128 + t];
    __shared__ double red[128];
    red[t] = s;
    __syncthreads();
    if (t < 64) {
        double a = red[t], c = red[64 + t];
        double M = (double)B * NN * KNN;
        double mean = a / M;
        double var  = c / M - mean * mean;
        float sc = gamma[t] * rsqrtf((float)var + 1e-5f);
        float sh = beta[t] - (float)mean * sc;
        ss[t]      = sc;
        ss[64 + t] = sh;
    }
}

// ---------------- K5: normalize + leakyrelu + transpose to (B,O,N) ----------------
__global__ __launch_bounds__(256) void k5_out(const float* __restrict__ maxY,
                                              const float* __restrict__ minY,
                                              const float* __restrict__ ss,
                                              float* __restrict__ out) {
    __shared__ float tile[64][65];
    __shared__ float sc[64], sh[64];
    int t = threadIdx.x;
    if (t < 64) { sc[t] = ss[t]; sh[t] = ss[64 + t]; }
    int b  = blockIdx.x / (NN / 64);
    int n0 = (blockIdx.x % (NN / 64)) * 64;
    __syncthreads();
    #pragma unroll
    for (int it = 0; it < 16; ++it) {
        int i = it * 256 + t;
        int nl = i >> 6, o = i & 63;
        size_t off = ((size_t)(b * NN + n0 + nl)) * 64 + o;
        float s = sc[o];
        float v = (s >= 0.f) ? maxY[off] : minY[off];
        v = fmaf(v, s, sh[o]);
        v = (v >= 0.f) ? v : 0.2f * v;
        tile[nl][o] = v;
    }
    __syncthreads();
    #pragma unroll
    for (int it = 0; it < 16; ++it) {
        int i = it * 256 + t;
        int o = i >> 6, nl = i & 63;
        out[((size_t)(b * O + o)) * NN + n0 + nl] = tile[nl][o];
    }
}

extern "C" void kernel_launch(void* const* d_in, const int* in_sizes, int n_in,
                              void* d_out, int out_size, void* d_ws, size_t ws_size,
                              hipStream_t stream) {
    const float* x     = (const float*)d_in[0];
    const float* W     = (const float*)d_in[1];
    const float* gamma = (const float*)d_in[2];
    const float* beta  = (const float*)d_in[3];
    float* out = (float*)d_out;

    float* ws = (float*)d_ws;
    float* xx = ws;                                                // B*N
    float* xt = xx + (size_t)B * NN;                               // B*N*C f32
    __hip_bfloat16* xh = (__hip_bfloat16*)(xt + (size_t)B * NN * C); // B*N*C bf16 (tiled)
    int*   idx = (int*)(xh + (size_t)B * NN * C);                  // B*N*KNN ints
    float* Z   = (float*)(idx + (size_t)B * NN * KNN);             // B*N*O
    float* Z2  = Z + (size_t)B * NN * O;
    float* maxY = Z2 + (size_t)B * NN * O;
    float* minY = maxY + (size_t)B * NN * O;
    float* partials  = minY + (size_t)B * NN * O;                  // (B*N/4)*128
    float* partials2 = partials + (size_t)(B * NN / 4) * 128;      // 64*128
    float* ss = partials2 + 64 * 128;                              // 128

    k1_split<<<B * (NN / 64), 256, 0, stream>>>(x, xt, xh, xx);
    k2_knn<<<B * (NN / 32), 256, 0, stream>>>(xh, xt, xx, idx);
    k3a_gemm<<<B * (NN / 16), 256, 0, stream>>>(xt, W, Z, Z2);
    k3b_gather<<<B * (NN / 4), 256, 0, stream>>>(Z, Z2, idx, maxY, minY, partials);
    k4a_reduce<<<64, 256, 0, stream>>>(partials, partials2);
    k4b_stats<<<1, 128, 0, stream>>>(partials2, gamma, beta, ss);
    k5_out<<<B * (NN / 64), 256, 0, stream>>>(maxY, minY, ss, out);
}

// Round 16
// 234.062 us; speedup vs baseline: 1.0693x; 1.0693x over previous
//
#include <hip/hip_runtime.h>
#include <hip/hip_bf16.h>
#include <math.h>

#define B 8
#define C 64
#define NN 4096
#define O 64
#define KNN 20

typedef float f32x4 __attribute__((ext_vector_type(4)));
typedef short short8_t __attribute__((ext_vector_type(8)));

__device__ inline uint32_t fkey(float f) {
    uint32_t u = __float_as_uint(f);
    return u ^ (((uint32_t)((int32_t)u >> 31)) | 0x80000000u);
}

__device__ inline uint32_t med3u(uint32_t a, uint32_t b, uint32_t c) {
    uint32_t r;
    asm("v_med3_u32 %0, %1, %2, %3" : "=v"(r) : "v"(a), "v"(b), "v"(c));
    return r;
}
__device__ inline uint32_t umax(uint32_t a, uint32_t b) { return a > b ? a : b; }
__device__ inline uint32_t umin(uint32_t a, uint32_t b) { return a < b ? a : b; }

// min-reduce over each 16-lane group, result in ALL 16 lanes. Pure VALU (DPP).
__device__ inline uint32_t minall16(uint32_t v) {
    uint32_t t;
    t = (uint32_t)__builtin_amdgcn_update_dpp(0, (int)v, 0x140, 0xF, 0xF, true); // row_mirror
    v = umin(v, t);
    t = (uint32_t)__builtin_amdgcn_update_dpp(0, (int)v, 0x141, 0xF, 0xF, true); // row_half_mirror
    v = umin(v, t);
    t = (uint32_t)__builtin_amdgcn_update_dpp(0, (int)v, 0x4E, 0xF, 0xF, true);  // quad_perm [2,3,0,1]
    v = umin(v, t);
    t = (uint32_t)__builtin_amdgcn_update_dpp(0, (int)v, 0xB1, 0xF, 0xF, true);  // quad_perm [1,0,3,2]
    v = umin(v, t);
    return v;
}

// tiled xh layout: element (n, c) -> tile(n>>4)*1024 + (c>>5)*512
//                                  + ((c&31)>>3)*128 + (n&15)*8 + (c&7)
// MFMA fragment loads are lane-contiguous: lane l reads 16B at tilebase+l*16B.

// ---------------- K1: x (B,C,N) -> xt f32 (B,N,C) + xh bf16 TILED, xx = sum_c x^2 ----------------
__global__ __launch_bounds__(256) void k1_split(const float* __restrict__ x,
                                                float* __restrict__ xt,
                                                __hip_bfloat16* __restrict__ xh,
                                                float* __restrict__ xx) {
    __shared__ float tile[64][65];
    int b  = blockIdx.x / (NN / 64);
    int n0 = (blockIdx.x % (NN / 64)) * 64;
    int t = threadIdx.x;
    #pragma unroll
    for (int it = 0; it < 16; ++it) {
        int i = it * 256 + t;
        int c = i >> 6, n = i & 63;
        tile[c][n] = x[(size_t)b * C * NN + (size_t)c * NN + n0 + n];
    }
    __syncthreads();
    #pragma unroll
    for (int it = 0; it < 16; ++it) {
        int i = it * 256 + t;
        int n = i >> 6, c = i & 63;
        float v = tile[c][n];
        xt[((size_t)(b * NN + n0 + n)) * C + c] = v;
        int tl   = (n0 + n) >> 4;
        int r    = n & 15;
        int half = c >> 5, cc = c & 31;
        int grp  = cc >> 3, e = cc & 7;
        size_t ta = (size_t)b * NN * 64 + (size_t)tl * 1024 + half * 512
                  + grp * 128 + r * 8 + e;
        xh[ta] = __float2bfloat16(v);
    }
    if (t < 64) {
        float s = 0.f;
        #pragma unroll
        for (int c = 0; c < 64; ++c) { float v = tile[c][t]; s = fmaf(v, v, s); }
        xx[(size_t)b * NN + t + n0] = s;
    }
}

// ---------------- K2: wave-autonomous KNN, coalesced tiled loads (R14 = best verified, 176us) ----------------
// Each WAVE owns 16 queries x ALL 4096 candidates (256 tiles). Grid 512;
// XCD swizzle b=blk&7 pins each batch to one XCD L2. Sweep loads are
// lane-contiguous 1KB wave transactions (tiled xh). Min-convention keys
// (d'=2a-xxc-xxq-2<0 -> raw as_uint orders inversely), packed (key20|col12);
// per-lane depth-12 min-queues via med3 (Binom(32,1/16): P(>=13)~2e-7).
// 4-deep prefetch; 32-round DPP min-tournament -> approx-top-32 pool;
// exact f32 rerank of 32 + rank-loop scatter (R4-validated semantics).
// NOTE: six structural variants (R8,R11-R15) bracket this kernel at 176-200us;
// occupancy 12-43% made no difference -> per-wave efficiency bound, accepted.
__global__ __launch_bounds__(256) void k2_knn(const __hip_bfloat16* __restrict__ xh,
                                              const float* __restrict__ xt,
                                              const float* __restrict__ xx,
                                              int* __restrict__ idx) {
    int b     = blockIdx.x & 7;
    int qbase = (blockIdx.x >> 3) << 6;       // 64 queries per block
    int t = threadIdx.x;
    int w = t >> 6, lane = t & 63;
    int laneid = lane & 15, grp = lane >> 4;
    int n0w = qbase + w * 16;                 // this wave's 16 queries

    const __hip_bfloat16* xhtb = xh + (size_t)b * NN * 64;   // tiled
    const float* xxb = xx + (size_t)b * NN;
    const float* xtb = xt + (size_t)b * NN * 64;

    const __hip_bfloat16* lp = xhtb + lane * 8;   // lane base in tiled layout

    // A fragments: query tile n0w>>4, lane-linear
    short8_t Ah0 = *(const short8_t*)(lp + (size_t)(n0w >> 4) * 1024);
    short8_t Ah1 = *(const short8_t*)(lp + (size_t)(n0w >> 4) * 1024 + 512);

    // per-query bias: -xxq - 2  (group's queries are n0w+grp*4+j)
    float bq[4];
    #pragma unroll
    for (int j = 0; j < 4; ++j) bq[j] = -2.f - xxb[n0w + grp * 4 + j];

    // per-lane sorted min-queues (ascending), packed (key20|col12)
    uint32_t qq[4][12];
    #pragma unroll
    for (int j = 0; j < 4; ++j)
        #pragma unroll
        for (int i = 0; i < 12; ++i) qq[j][i] = 0xFFFFFFFFu;

    // ---- sweep: 256 tiles, 4-deep register pipeline, contiguous loads ----
    short8_t P00, P01, P10, P11, P20, P21, P30, P31;
    float Px0, Px1, Px2, Px3;
    P00 = *(const short8_t*)(lp);        P01 = *(const short8_t*)(lp + 512);
    P10 = *(const short8_t*)(lp + 1024); P11 = *(const short8_t*)(lp + 1536);
    P20 = *(const short8_t*)(lp + 2048); P21 = *(const short8_t*)(lp + 2560);
    P30 = *(const short8_t*)(lp + 3072); P31 = *(const short8_t*)(lp + 3584);
    Px0 = xxb[laneid];      Px1 = xxb[laneid + 16];
    Px2 = xxb[laneid + 32]; Px3 = xxb[laneid + 48];

// body K: compute tile tt+K, prefetch tile tt+4+K (lane-contiguous, imm offsets).
// Tail prefetches read <=16KB past this batch's xh/xx into adjacent workspace
// arrays — allocated memory, values never consumed.
#define SWEEP_BODY(PB0, PB1, PXX, K, PF, OFF)                                  \
    {                                                                          \
        float xxc = PXX;                                                       \
        f32x4 acc = {0.f, 0.f, 0.f, 0.f};                                      \
        acc = __builtin_amdgcn_mfma_f32_16x16x32_bf16(Ah0, PB0, acc, 0, 0, 0); \
        acc = __builtin_amdgcn_mfma_f32_16x16x32_bf16(Ah1, PB1, acc, 0, 0, 0); \
        PB0 = *(const short8_t*)(PF + OFF);                                    \
        PB1 = *(const short8_t*)(PF + OFF + 512);                              \
        PXX = xxb[ci0 + (4 + K) * 16];                                         \
        uint32_t ci = (uint32_t)(ci0 + K * 16);                                \
        _Pragma("unroll")                                                      \
        for (int j = 0; j < 4; ++j) {                                          \
            uint32_t u = __float_as_uint(fmaf(acc[j], 2.f, bq[j] - xxc));      \
            uint32_t nv = (u & 0xFFFFF000u) | ci;                              \
            _Pragma("unroll")                                                  \
            for (int i = 11; i >= 1; --i)                                      \
                qq[j][i] = med3u(qq[j][i - 1], qq[j][i], nv);                  \
            qq[j][0] = umin(qq[j][0], nv);                                     \
        }                                                                      \
    }

    #pragma unroll 1
    for (int tt = 0; tt < 256; tt += 4) {
        int ci0 = tt * 16 + laneid;
        const __hip_bfloat16* pf0 = lp + (size_t)(tt + 4) * 1024;
        const __hip_bfloat16* pf2 = pf0 + 2048;
        SWEEP_BODY(P00, P01, Px0, 0, pf0, 0)
        SWEEP_BODY(P10, P11, Px1, 1, pf0, 1024)
        SWEEP_BODY(P20, P21, Px2, 2, pf2, 0)
        SWEEP_BODY(P30, P31, Px3, 3, pf2, 1024)
    }
#undef SWEEP_BODY

    __shared__ uint32_t cand[4][16][33];   // per-wave pools (padded stride 33)
    __shared__ uint32_t rkk[4][16][33];    // exact f32 keys (padded)
    __shared__ float qrow[4][16][68];      // f32 query rows (padded)

    // stage f32 query rows (global loads overlap extraction)
    #pragma unroll
    for (int i = 0; i < 16; ++i)
        qrow[w][i][lane] = xtb[(size_t)(n0w + i) * 64 + lane];

    // ---- extraction: 32-round DPP min-tournament over 16 queue heads ----
    #pragma unroll 1
    for (int r = 0; r < 32; ++r) {
        #pragma unroll
        for (int j = 0; j < 4; ++j) {
            uint32_t bk = minall16(qq[j][0]);
            bool win = (qq[j][0] == bk);   // packed values unique -> single winner
            #pragma unroll
            for (int i = 0; i < 11; ++i) qq[j][i] = win ? qq[j][i + 1] : qq[j][i];
            qq[j][11] = win ? 0xFFFFFFFFu : qq[j][11];
            if (laneid == 0) cand[w][grp * 4 + j][r] = bk & 4095u;
        }
    }
    __syncthreads();   // non-critical safety (waves are independent)

    // ---- exact f32 rerank of the 32-pool (Round-1 arithmetic), 8 entries/lane ----
    int rq = lane >> 2, rs = lane & 3;     // 16 queries x 4 lanes each
    float qxx = xxb[n0w + rq];
    const float4* qr = (const float4*)qrow[w][rq];
    uint32_t ky[8], cl[8];
    #pragma unroll
    for (int e = 0; e < 8; ++e) {
        uint32_t col = cand[w][rq][rs + 4 * e];
        const float4* cr = (const float4*)(xtb + (size_t)col * 64);
        float a = 0.f;
        #pragma unroll
        for (int i = 0; i < 16; ++i) {
            float4 qv = qr[i], cv = cr[i];
            a = fmaf(qv.x, cv.x, a); a = fmaf(qv.y, cv.y, a);
            a = fmaf(qv.z, cv.z, a); a = fmaf(qv.w, cv.w, a);
        }
        float d = 2.f * a - qxx - xxb[col];
        ky[e] = fkey(d);
        cl[e] = col;
        rkk[w][rq][rs + 4 * e] = ky[e];
    }
    __syncthreads();

    // ---- rank loop: exact position among the 32, scatter top-20 ----
    int rank[8];
    #pragma unroll
    for (int e = 0; e < 8; ++e) rank[e] = 0;
    #pragma unroll
    for (int jj = 0; jj < 32; ++jj) {
        uint32_t kj = rkk[w][rq][jj], cj = cand[w][rq][jj];
        #pragma unroll
        for (int e = 0; e < 8; ++e)
            rank[e] += (kj > ky[e] || (kj == ky[e] && cj < cl[e])) ? 1 : 0;
    }
    size_t ob = ((size_t)(b * NN) + n0w + rq) * KNN;
    #pragma unroll
    for (int e = 0; e < 8; ++e)
        if (rank[e] < KNN) idx[ob + rank[e]] = (int)cl[e];
}

// ---------------- K3a: Z = xt @ W0^T, Z2 = xt @ (W1-W0)^T ----------------
__global__ __launch_bounds__(256) void k3a_gemm(const float* __restrict__ xt,
                                                const float* __restrict__ W,
                                                float* __restrict__ Z,
                                                float* __restrict__ Z2) {
    __shared__ float W0t[64][65];
    __shared__ float W21t[64][65];
    __shared__ float xs[16][64];
    int t = threadIdx.x;
    #pragma unroll
    for (int it = 0; it < 16; ++it) {
        int i = it * 256 + t;
        int o = i >> 6, c = i & 63;
        float w0 = W[o * 128 + c];
        float w1 = W[o * 128 + 64 + c];
        W0t[c][o]  = w0;
        W21t[c][o] = w1 - w0;
    }
    int b  = blockIdx.x / (NN / 16);
    int nb = (blockIdx.x % (NN / 16)) * 16;
    #pragma unroll
    for (int it = 0; it < 4; ++it) {
        int i = it * 256 + t;
        int r = i >> 6, c = i & 63;
        xs[r][c] = xt[((size_t)(b * NN + nb + r)) * C + c];
    }
    __syncthreads();
    int o = t & 63, rg = t >> 6;
    #pragma unroll
    for (int rr = 0; rr < 4; ++rr) {
        int r = rg * 4 + rr;
        float z = 0.f, z2 = 0.f;
        #pragma unroll
        for (int c = 0; c < 64; ++c) {
            float xv = xs[r][c];
            z  = fmaf(xv, W0t[c][o],  z);
            z2 = fmaf(xv, W21t[c][o], z2);
        }
        size_t off = ((size_t)(b * NN + nb + r)) * 64 + o;
        Z[off]  = z;
        Z2[off] = z2;
    }
}

// ---------------- K3b: gather neighbors, per-(b,n,o) max/min over k, block-partial sums ----------------
// XCD swizzle: b = blockIdx&7 pins each batch's Z/Z2 (2MB) to one XCD's L2.
__global__ __launch_bounds__(256) void k3b_gather(const float* __restrict__ Z,
                                                  const float* __restrict__ Z2,
                                                  const int* __restrict__ idx,
                                                  float* __restrict__ maxY,
                                                  float* __restrict__ minY,
                                                  float* __restrict__ partials) {
    int t = threadIdx.x;
    int p = t >> 6, o = t & 63;
    int b = blockIdx.x & 7;
    int n = (blockIdx.x >> 3) * 4 + p;
    size_t base = (size_t)(b * NN + n);
    float z2 = Z2[base * 64 + o];
    __shared__ int sidx[4][KNN];
    if (o < KNN) sidx[p][o] = idx[base * KNN + o];
    __syncthreads();
    const float* Zb = Z + (size_t)b * NN * 64;
    float s1 = 0.f, s2 = 0.f, mx = -INFINITY, mn = INFINITY;
    #pragma unroll
    for (int k = 0; k < KNN; ++k) {
        float y = Zb[(size_t)sidx[p][k] * 64 + o] + z2;
        s1 += y;
        s2 = fmaf(y, y, s2);
        mx = fmaxf(mx, y);
        mn = fminf(mn, y);
    }
    maxY[base * 64 + o] = mx;
    minY[base * 64 + o] = mn;
    __shared__ float red[2][4][64];
    red[0][p][o] = s1;
    red[1][p][o] = s2;
    __syncthreads();
    if (t < 64) {
        float a = red[0][0][t] + red[0][1][t] + red[0][2][t] + red[0][3][t];
        float c = red[1][0][t] + red[1][1][t] + red[1][2][t] + red[1][3][t];
        partials[(size_t)blockIdx.x * 128 + t]      = a;
        partials[(size_t)blockIdx.x * 128 + 64 + t] = c;
    }
}

// ---------------- K4a: reduce 8192 partial rows -> 64 rows ----------------
__global__ __launch_bounds__(256) void k4a_reduce(const float* __restrict__ partials,
                                                  float* __restrict__ partials2) {
    int g = blockIdx.x;          // 0..63
    int t = threadIdx.x;
    int col = t & 127, half = t >> 7;
    float s = 0.f;
    for (int r = half; r < 128; r += 2)
        s += partials[((size_t)g * 128 + r) * 128 + col];
    __shared__ float red[2][128];
    red[half][col] = s;
    __syncthreads();
    if (t < 128) partials2[(size_t)g * 128 + t] = red[0][t] + red[1][t];
}

// ---------------- K5: stats (fused ex-k4b) + normalize + leakyrelu + transpose to (B,O,N) ----------------
// Each block recomputes channel stats from partials2 (64x128 f32 = 32KB,
// L2/L3-resident; SAME sequential f64 summation order as the old k4b ->
// bit-identical, deterministic), then applies scale/shift/LeakyReLU/transpose.
__global__ __launch_bounds__(256) void k5_out(const float* __restrict__ partials2,
                                              const float* __restrict__ gamma,
                                              const float* __restrict__ beta,
                                              const float* __restrict__ maxY,
                                              const float* __restrict__ minY,
                                              float* __restrict__ out) {
    __shared__ float tile[64][65];
    __shared__ double red[128];
    __shared__ float sc[64], sh[64];
    int t = threadIdx.x;
    if (t < 128) {
        double s = 0.0;
        for (int i = 0; i < 64; ++i)
            s += (double)partials2[(size_t)i * 128 + t];
        red[t] = s;
    }
    __syncthreads();
    if (t < 64) {
        double a = red[t], c = red[64 + t];
        double M = (double)B * NN * KNN;
        double mean = a / M;
        double var  = c / M - mean * mean;
        float s = gamma[t] * rsqrtf((float)var + 1e-5f);
        sc[t] = s;
        sh[t] = beta[t] - (float)mean * s;
    }
    int b  = blockIdx.x / (NN / 64);
    int n0 = (blockIdx.x % (NN / 64)) * 64;
    __syncthreads();
    #pragma unroll
    for (int it = 0; it < 16; ++it) {
        int i = it * 256 + t;
        int nl = i >> 6, o = i & 63;
        size_t off = ((size_t)(b * NN + n0 + nl)) * 64 + o;
        float s = sc[o];
        float v = (s >= 0.f) ? maxY[off] : minY[off];
        v = fmaf(v, s, sh[o]);
        v = (v >= 0.f) ? v : 0.2f * v;
        tile[nl][o] = v;
    }
    __syncthreads();
    #pragma unroll
    for (int it = 0; it < 16; ++it) {
        int i = it * 256 + t;
        int o = i >> 6, nl = i & 63;
        out[((size_t)(b * O + o)) * NN + n0 + nl] = tile[nl][o];
    }
}

extern "C" void kernel_launch(void* const* d_in, const int* in_sizes, int n_in,
                              void* d_out, int out_size, void* d_ws, size_t ws_size,
                              hipStream_t stream) {
    const float* x     = (const float*)d_in[0];
    const float* W     = (const float*)d_in[1];
    const float* gamma = (const float*)d_in[2];
    const float* beta  = (const float*)d_in[3];
    float* out = (float*)d_out;

    float* ws = (float*)d_ws;
    float* xx = ws;                                                // B*N
    float* xt = xx + (size_t)B * NN;                               // B*N*C f32
    __hip_bfloat16* xh = (__hip_bfloat16*)(xt + (size_t)B * NN * C); // B*N*C bf16 (tiled)
    int*   idx = (int*)(xh + (size_t)B * NN * C);                  // B*N*KNN ints
    float* Z   = (float*)(idx + (size_t)B * NN * KNN);             // B*N*O
    float* Z2  = Z + (size_t)B * NN * O;
    float* maxY = Z2 + (size_t)B * NN * O;
    float* minY = maxY + (size_t)B * NN * O;
    float* partials  = minY + (size_t)B * NN * O;                  // (B*N/4)*128
    float* partials2 = partials + (size_t)(B * NN / 4) * 128;      // 64*128

    k1_split<<<B * (NN / 64), 256, 0, stream>>>(x, xt, xh, xx);
    k2_knn<<<B * (NN / 64), 256, 0, stream>>>(xh, xt, xx, idx);
    k3a_gemm<<<B * (NN / 16), 256, 0, stream>>>(xt, W, Z, Z2);
    k3b_gather<<<B * (NN / 4), 256, 0, stream>>>(Z, Z2, idx, maxY, minY, partials);
    k4a_reduce<<<64, 256, 0, stream>>>(partials, partials2);
    k5_out<<<B * (NN / 64), 256, 0, stream>>>(partials2, gamma, beta, maxY, minY, out);
}